// Round 5
// baseline (428.088 us; speedup 1.0000x reference)
//
#include <hip/hip_runtime.h>

#define GB 8          // batch (graphs)
#define GN 4096       // nodes (2^12)
#define GH 64         // hidden
#define GE 131072     // edges per graph (2^17)
#define LN_EPS 1e-5f
#define NBIN (GB * GN)   // 32768 destination bins
#define TOTE (GB * GE)   // 1048576 total edges

static __device__ __forceinline__ unsigned short f2bf(float f) {
    union { float f; unsigned int u; } v; v.f = f;
    unsigned int u = v.u;
    return (unsigned short)((u + 0x7FFFu + ((u >> 16) & 1u)) >> 16);
}
static __device__ __forceinline__ void bf2x(unsigned int u, float& lo, float& hi) {
    union { float f; unsigned int i; } a, b;
    a.i = u << 16; b.i = u & 0xFFFF0000u;
    lo = a.f; hi = b.f;
}
static __device__ __forceinline__ void fma8(uint4 ev, uint4 hv, float4& a0, float4& a1) {
    float el, eh, hl, hh;
    bf2x(ev.x, el, eh); bf2x(hv.x, hl, hh);
    a0.x = fmaf(el, hl, a0.x); a0.y = fmaf(eh, hh, a0.y);
    bf2x(ev.y, el, eh); bf2x(hv.y, hl, hh);
    a0.z = fmaf(el, hl, a0.z); a0.w = fmaf(eh, hh, a0.w);
    bf2x(ev.z, el, eh); bf2x(hv.z, hl, hh);
    a1.x = fmaf(el, hl, a1.x); a1.y = fmaf(eh, hh, a1.y);
    bf2x(ev.w, el, eh); bf2x(hv.w, hl, hh);
    a1.z = fmaf(el, hl, a1.z); a1.w = fmaf(eh, hh, a1.w);
}

// ---- presence mask: wave-per-node sum over H ----
__global__ void k_init(const float* __restrict__ nf, float* __restrict__ pres) {
    int w = (blockIdx.x * blockDim.x + threadIdx.x) >> 6;
    int lane = threadIdx.x & 63;
    if (w >= NBIN) return;
    float v = nf[(size_t)w * GH + lane];
    #pragma unroll
    for (int o = 1; o < 64; o <<= 1) v += __shfl_xor(v, o, 64);
    if (lane == 0) pres[w] = (v != 0.0f) ? 1.0f : 0.0f;
}

// ---- histogram of destinations ----
__global__ void k_hist(const int* __restrict__ ei, int* __restrict__ hist) {
    int t = blockIdx.x * blockDim.x + threadIdx.x;   // < TOTE
    int b = t >> 17, e = t & (GE - 1);
    int dst = ei[(b << 18) + GE + e];
    atomicAdd(&hist[(b << 12) + dst], 1);
}

// ---- per-graph exclusive scan of 4096 bins (256 thr x 16 bins) ----
__global__ void k_scan(const int* __restrict__ hist, int* __restrict__ off,
                       int* __restrict__ cur) {
    __shared__ int part[256];
    int b = blockIdx.x;
    int t = threadIdx.x;
    int base = (b << 12) + t * 16;
    int c[16];
    int s = 0;
    #pragma unroll
    for (int i = 0; i < 16; ++i) { c[i] = hist[base + i]; s += c[i]; }
    part[t] = s;
    __syncthreads();
    for (int o = 1; o < 256; o <<= 1) {
        int u = (t >= o) ? part[t - o] : 0;
        __syncthreads();
        part[t] += u;
        __syncthreads();
    }
    int p = b * GE + part[t] - s;   // global exclusive prefix (graph base b*GE)
    #pragma unroll
    for (int i = 0; i < 16; ++i) { off[base + i] = p; cur[base + i] = p; p += c[i]; }
    if (b == GB - 1 && t == 255) off[NBIN] = TOTE;
}

// ---- fill + permute: copy each ea row (as bf16) to its dst-sorted slot ----
__global__ void k_fillperm(const int* __restrict__ ei, int* __restrict__ cur,
                           const float* __restrict__ ea,
                           int* __restrict__ sSrc, unsigned short* __restrict__ ea_s) {
    int grp = (blockIdx.x * blockDim.x + threadIdx.x) >> 4;   // edge id
    if (grp >= TOTE) return;
    int sub  = threadIdx.x & 15;
    int lane = threadIdx.x & 63;
    int b = grp >> 17, e = grp & (GE - 1);
    int dst = ei[(b << 18) + GE + e];
    int pos = 0;
    if (sub == 0) pos = atomicAdd(&cur[(b << 12) + dst], 1);
    pos = __shfl(pos, lane & ~15, 64);    // broadcast from group leader
    float4 v = *reinterpret_cast<const float4*>(ea + ((size_t)grp << 6) + (sub << 2));
    ushort4 o;
    o.x = f2bf(v.x); o.y = f2bf(v.y); o.z = f2bf(v.z); o.w = f2bf(v.w);
    *reinterpret_cast<ushort4*>(ea_s + ((size_t)pos << 6) + (sub << 2)) = o;
    if (sub == 0) sSrc[pos] = ei[(b << 18) + e];
}

// ---- h = x @ W[layer] -> bf16; W staged in LDS; wave-per-row ----
__global__ void k_gemm(const float* __restrict__ x, const float* __restrict__ W,
                       unsigned short* __restrict__ h, int layer) {
    __shared__ float Wl[GH * GH];
    for (int i = threadIdx.x; i < GH * GH; i += blockDim.x)
        Wl[i] = W[layer * GH * GH + i];
    __syncthreads();
    int w = (blockIdx.x * blockDim.x + threadIdx.x) >> 6;
    int lane = threadIdx.x & 63;
    if (w >= NBIN) return;
    float xv = x[(size_t)w * GH + lane];
    float acc = 0.0f;
    #pragma unroll
    for (int k = 0; k < GH; ++k)
        acc = fmaf(__shfl(xv, k, 64), Wl[k * GH + lane], acc);
    h[(size_t)w * GH + lane] = f2bf(acc);
}

// ---- gather: 8-lane group per destination bin, shfl-free streaming loop ----
__global__ void k_gather(const int* __restrict__ off, const int* __restrict__ sSrc,
                         const unsigned short* __restrict__ ea_s,
                         const unsigned short* __restrict__ h,
                         const float* __restrict__ bias, const float* __restrict__ gam,
                         const float* __restrict__ bet,
                         float* __restrict__ x, const float* __restrict__ pres,
                         const float* __restrict__ ge, float* __restrict__ out,
                         int layer) {
    int w = (blockIdx.x * blockDim.x + threadIdx.x) >> 3;   // bin id
    if (w >= NBIN) return;
    int sub = threadIdx.x & 7;                              // lane within group
    int b = w >> 12;
    int beg = off[w], end = off[w + 1];
    const unsigned short* hb = h + ((((size_t)b) << 12) * GH);

    float4 a0 = make_float4(0.f, 0.f, 0.f, 0.f);
    float4 a1 = make_float4(0.f, 0.f, 0.f, 0.f);
    int e = beg;
    for (; e + 4 <= end; e += 4) {
        int s0 = sSrc[e + 0];
        int s1 = sSrc[e + 1];
        int s2 = sSrc[e + 2];
        int s3 = sSrc[e + 3];
        uint4 ev0 = *reinterpret_cast<const uint4*>(ea_s + (((size_t)(e + 0)) << 6) + (sub << 3));
        uint4 ev1 = *reinterpret_cast<const uint4*>(ea_s + (((size_t)(e + 1)) << 6) + (sub << 3));
        uint4 ev2 = *reinterpret_cast<const uint4*>(ea_s + (((size_t)(e + 2)) << 6) + (sub << 3));
        uint4 ev3 = *reinterpret_cast<const uint4*>(ea_s + (((size_t)(e + 3)) << 6) + (sub << 3));
        uint4 hv0 = *reinterpret_cast<const uint4*>(hb + (((size_t)s0) << 6) + (sub << 3));
        uint4 hv1 = *reinterpret_cast<const uint4*>(hb + (((size_t)s1) << 6) + (sub << 3));
        uint4 hv2 = *reinterpret_cast<const uint4*>(hb + (((size_t)s2) << 6) + (sub << 3));
        uint4 hv3 = *reinterpret_cast<const uint4*>(hb + (((size_t)s3) << 6) + (sub << 3));
        fma8(ev0, hv0, a0, a1);
        fma8(ev1, hv1, a0, a1);
        fma8(ev2, hv2, a0, a1);
        fma8(ev3, hv3, a0, a1);
    }
    for (; e < end; ++e) {
        int s0 = sSrc[e];
        uint4 ev = *reinterpret_cast<const uint4*>(ea_s + (((size_t)e) << 6) + (sub << 3));
        uint4 hv = *reinterpret_cast<const uint4*>(hb + (((size_t)s0) << 6) + (sub << 3));
        fma8(ev, hv, a0, a1);
    }

    // epilogue: bias + relu + LN (+ residual / final blend); 8-lane reductions
    const float4* bias4 = reinterpret_cast<const float4*>(bias + layer * GH + (sub << 3));
    float4 b0 = bias4[0], b1 = bias4[1];
    float4 v0, v1;
    v0.x = fmaxf(a0.x + b0.x, 0.f); v0.y = fmaxf(a0.y + b0.y, 0.f);
    v0.z = fmaxf(a0.z + b0.z, 0.f); v0.w = fmaxf(a0.w + b0.w, 0.f);
    v1.x = fmaxf(a1.x + b1.x, 0.f); v1.y = fmaxf(a1.y + b1.y, 0.f);
    v1.z = fmaxf(a1.z + b1.z, 0.f); v1.w = fmaxf(a1.w + b1.w, 0.f);
    float s = v0.x + v0.y + v0.z + v0.w + v1.x + v1.y + v1.z + v1.w;
    #pragma unroll
    for (int o = 1; o < 8; o <<= 1) s += __shfl_xor(s, o, 64);
    float mu = s * (1.0f / GH);
    float4 d0, d1;
    d0.x = v0.x - mu; d0.y = v0.y - mu; d0.z = v0.z - mu; d0.w = v0.w - mu;
    d1.x = v1.x - mu; d1.y = v1.y - mu; d1.z = v1.z - mu; d1.w = v1.w - mu;
    float q = d0.x*d0.x + d0.y*d0.y + d0.z*d0.z + d0.w*d0.w
            + d1.x*d1.x + d1.y*d1.y + d1.z*d1.z + d1.w*d1.w;
    #pragma unroll
    for (int o = 1; o < 8; o <<= 1) q += __shfl_xor(q, o, 64);
    float r = rsqrtf(q * (1.0f / GH) + LN_EPS);
    const float4* gam4 = reinterpret_cast<const float4*>(gam + layer * GH + (sub << 3));
    const float4* bet4 = reinterpret_cast<const float4*>(bet + layer * GH + (sub << 3));
    float4 g0 = gam4[0], g1 = gam4[1];
    float4 t0 = bet4[0], t1 = bet4[1];
    float4 y0, y1;
    y0.x = d0.x * r * g0.x + t0.x; y0.y = d0.y * r * g0.y + t0.y;
    y0.z = d0.z * r * g0.z + t0.z; y0.w = d0.w * r * g0.w + t0.w;
    y1.x = d1.x * r * g1.x + t1.x; y1.y = d1.y * r * g1.y + t1.y;
    y1.z = d1.z * r * g1.z + t1.z; y1.w = d1.w * r * g1.w + t1.w;

    float4* xp = reinterpret_cast<float4*>(x + (size_t)w * GH + (sub << 3));
    if (layer > 0) {
        float4 x0 = xp[0], x1 = xp[1];
        y0.x += x0.x; y0.y += x0.y; y0.z += x0.z; y0.w += x0.w;
        y1.x += x1.x; y1.y += x1.y; y1.z += x1.z; y1.w += x1.w;
    }
    if (layer < 2) {
        xp[0] = y0; xp[1] = y1;
    } else {
        float p = pres[w];
        const float4* ge4 = reinterpret_cast<const float4*>(ge + (size_t)(w & (GN - 1)) * GH + (sub << 3));
        float4 e0 = ge4[0], e1 = ge4[1];
        float4 o0, o1;
        o0.x = y0.x * p + e0.x * (1.f - p); o0.y = y0.y * p + e0.y * (1.f - p);
        o0.z = y0.z * p + e0.z * (1.f - p); o0.w = y0.w * p + e0.w * (1.f - p);
        o1.x = y1.x * p + e1.x * (1.f - p); o1.y = y1.y * p + e1.y * (1.f - p);
        o1.z = y1.z * p + e1.z * (1.f - p); o1.w = y1.w * p + e1.w * (1.f - p);
        float4* op = reinterpret_cast<float4*>(out + (size_t)w * GH + (sub << 3));
        op[0] = o0; op[1] = o1;
    }
}

extern "C" void kernel_launch(void* const* d_in, const int* in_sizes, int n_in,
                              void* d_out, int out_size, void* d_ws, size_t ws_size,
                              hipStream_t stream) {
    const float* nf = (const float*)d_in[0];   // node_features f32 [8,4096,64]
    const int* ei   = (const int*)d_in[1];     // edge_indices int32 [8,2,131072]
    const float* ea = (const float*)d_in[2];   // edge_attrs f32 [8,131072,64]
    const float* W  = (const float*)d_in[3];   // [3,64,64]
    const float* bb = (const float*)d_in[4];   // [3,64]
    const float* gg = (const float*)d_in[5];   // gamma [3,64]
    const float* be = (const float*)d_in[6];   // beta  [3,64]
    const float* ge = (const float*)d_in[7];   // global_emb [4096,64]
    float* out = (float*)d_out;

    float* x    = (float*)d_ws;                       // [B*N,H] f32   (8 MB)
    float* pres = x + (size_t)NBIN * GH;              // [B*N]
    int* off    = (int*)(pres + NBIN);                // [NBIN+1]
    int* cur    = off + NBIN + 1;                     // [NBIN]
    int* hist   = cur + NBIN;                         // [NBIN]
    int* sSrc   = hist + NBIN;                        // [TOTE]        (4 MB)
    unsigned short* h_s  = (unsigned short*)(sSrc + TOTE);        // [B*N,H] bf16 (4 MB)
    unsigned short* ea_s = h_s + (size_t)NBIN * GH;               // [TOTE,H] bf16 (128 MB)

    hipMemsetAsync(hist, 0, NBIN * sizeof(int), stream);
    k_init<<<NBIN / 4, 256, 0, stream>>>(nf, pres);
    k_hist<<<TOTE / 256, 256, 0, stream>>>(ei, hist);
    k_scan<<<GB, 256, 0, stream>>>(hist, off, cur);
    k_fillperm<<<TOTE / 16, 256, 0, stream>>>(ei, cur, ea, sSrc, ea_s);

    for (int l = 0; l < 3; ++l) {
        k_gemm<<<NBIN / 4, 256, 0, stream>>>(l == 0 ? nf : x, W, h_s, l);
        k_gather<<<NBIN * 8 / 256, 256, 0, stream>>>(off, sSrc, ea_s, h_s, bb, gg, be,
                                                     x, pres, ge, out, l);
    }
}

// Round 6
// 403.626 us; speedup vs baseline: 1.0606x; 1.0606x over previous
//
#include <hip/hip_runtime.h>

#define GB 8          // batch (graphs)
#define GN 4096       // nodes (2^12)
#define GH 64         // hidden
#define GE 131072     // edges per graph (2^17)
#define LN_EPS 1e-5f
#define NBIN (GB * GN)   // 32768 destination bins
#define TOTE (GB * GE)   // 1048576 total edges

static __device__ __forceinline__ unsigned short f2bf(float f) {
    union { float f; unsigned int u; } v; v.f = f;
    unsigned int u = v.u;
    return (unsigned short)((u + 0x7FFFu + ((u >> 16) & 1u)) >> 16);
}
static __device__ __forceinline__ void bf2x(unsigned int u, float& lo, float& hi) {
    union { float f; unsigned int i; } a, b;
    a.i = u << 16; b.i = u & 0xFFFF0000u;
    lo = a.f; hi = b.f;
}
static __device__ __forceinline__ void fma8(uint4 ev, uint4 hv, float4& a0, float4& a1) {
    float el, eh, hl, hh;
    bf2x(ev.x, el, eh); bf2x(hv.x, hl, hh);
    a0.x = fmaf(el, hl, a0.x); a0.y = fmaf(eh, hh, a0.y);
    bf2x(ev.y, el, eh); bf2x(hv.y, hl, hh);
    a0.z = fmaf(el, hl, a0.z); a0.w = fmaf(eh, hh, a0.w);
    bf2x(ev.z, el, eh); bf2x(hv.z, hl, hh);
    a1.x = fmaf(el, hl, a1.x); a1.y = fmaf(eh, hh, a1.y);
    bf2x(ev.w, el, eh); bf2x(hv.w, hl, hh);
    a1.z = fmaf(el, hl, a1.z); a1.w = fmaf(eh, hh, a1.w);
}

// ---- presence mask: wave-per-node sum over H ----
__global__ void k_init(const float* __restrict__ nf, float* __restrict__ pres) {
    int w = (blockIdx.x * blockDim.x + threadIdx.x) >> 6;
    int lane = threadIdx.x & 63;
    if (w >= NBIN) return;
    float v = nf[(size_t)w * GH + lane];
    #pragma unroll
    for (int o = 1; o < 64; o <<= 1) v += __shfl_xor(v, o, 64);
    if (lane == 0) pres[w] = (v != 0.0f) ? 1.0f : 0.0f;
}

// ---- histogram of destinations ----
__global__ void k_hist(const int* __restrict__ ei, int* __restrict__ hist) {
    int t = blockIdx.x * blockDim.x + threadIdx.x;   // < TOTE
    int b = t >> 17, e = t & (GE - 1);
    int dst = ei[(b << 18) + GE + e];
    atomicAdd(&hist[(b << 12) + dst], 1);
}

// ---- per-graph exclusive scan of 4096 bins (256 thr x 16 bins) ----
__global__ void k_scan(const int* __restrict__ hist, int* __restrict__ off,
                       int* __restrict__ cur) {
    __shared__ int part[256];
    int b = blockIdx.x;
    int t = threadIdx.x;
    int base = (b << 12) + t * 16;
    int c[16];
    int s = 0;
    #pragma unroll
    for (int i = 0; i < 16; ++i) { c[i] = hist[base + i]; s += c[i]; }
    part[t] = s;
    __syncthreads();
    for (int o = 1; o < 256; o <<= 1) {
        int u = (t >= o) ? part[t - o] : 0;
        __syncthreads();
        part[t] += u;
        __syncthreads();
    }
    int p = b * GE + part[t] - s;   // global exclusive prefix (graph base b*GE)
    #pragma unroll
    for (int i = 0; i < 16; ++i) { off[base + i] = p; cur[base + i] = p; p += c[i]; }
    if (b == GB - 1 && t == 255) off[NBIN] = TOTE;
}

// ---- fill + permute: copy each ea row (as bf16) to its dst-sorted slot ----
__global__ void k_fillperm(const int* __restrict__ ei, int* __restrict__ cur,
                           const float* __restrict__ ea,
                           int* __restrict__ sSrc, unsigned short* __restrict__ ea_s) {
    int grp = (blockIdx.x * blockDim.x + threadIdx.x) >> 4;   // edge id
    if (grp >= TOTE) return;
    int sub  = threadIdx.x & 15;
    int lane = threadIdx.x & 63;
    int b = grp >> 17, e = grp & (GE - 1);
    int dst = ei[(b << 18) + GE + e];
    int pos = 0;
    if (sub == 0) pos = atomicAdd(&cur[(b << 12) + dst], 1);
    pos = __shfl(pos, lane & ~15, 64);    // broadcast from group leader
    float4 v = *reinterpret_cast<const float4*>(ea + ((size_t)grp << 6) + (sub << 2));
    ushort4 o;
    o.x = f2bf(v.x); o.y = f2bf(v.y); o.z = f2bf(v.z); o.w = f2bf(v.w);
    *reinterpret_cast<ushort4*>(ea_s + ((size_t)pos << 6) + (sub << 2)) = o;
    if (sub == 0) sSrc[pos] = ei[(b << 18) + e];
}

// ---- h = x @ W[layer] -> bf16; W staged in LDS; wave-per-row ----
__global__ void k_gemm(const float* __restrict__ x, const float* __restrict__ W,
                       unsigned short* __restrict__ h, int layer) {
    __shared__ float Wl[GH * GH];
    for (int i = threadIdx.x; i < GH * GH; i += blockDim.x)
        Wl[i] = W[layer * GH * GH + i];
    __syncthreads();
    int w = (blockIdx.x * blockDim.x + threadIdx.x) >> 6;
    int lane = threadIdx.x & 63;
    if (w >= NBIN) return;
    float xv = x[(size_t)w * GH + lane];
    float acc = 0.0f;
    #pragma unroll
    for (int k = 0; k < GH; ++k)
        acc = fmaf(__shfl(xv, k, 64), Wl[k * GH + lane], acc);
    h[(size_t)w * GH + lane] = f2bf(acc);
}

// ---- gather: ONE BIN PER WAVE; each trip reads 8 edges as one contiguous 1KB block ----
// lane = (g = lane>>3 edge slot, sub = lane&7 feature oct)
__global__ void k_gather(const int* __restrict__ off, const int* __restrict__ sSrc,
                         const unsigned short* __restrict__ ea_s,
                         const unsigned short* __restrict__ h,
                         const float* __restrict__ bias, const float* __restrict__ gam,
                         const float* __restrict__ bet,
                         float* __restrict__ x, const float* __restrict__ pres,
                         const float* __restrict__ ge, float* __restrict__ out,
                         int layer) {
    int w = (blockIdx.x * blockDim.x + threadIdx.x) >> 6;   // bin id = wave id
    if (w >= NBIN) return;
    int lane = threadIdx.x & 63;
    int g   = lane >> 3;      // edge slot within trip (0..7)
    int sub = lane & 7;       // feature oct (0..7)
    int b = w >> 12;
    int beg = off[w], end = off[w + 1];
    const unsigned short* hb = h + ((((size_t)b) << 12) * GH);

    float4 a0 = make_float4(0.f, 0.f, 0.f, 0.f);
    float4 a1 = make_float4(0.f, 0.f, 0.f, 0.f);
    // unrolled x2: 16 edges (two 1KB contiguous blocks) in flight per iteration
    for (int e = beg; e < end; e += 16) {
        int e0 = e + g;
        int e1 = e + 8 + g;
        if (e0 < end) {
            int s0 = sSrc[e0];
            uint4 ev = *reinterpret_cast<const uint4*>(ea_s + (((size_t)e0) << 6) + (sub << 3));
            uint4 hv = *reinterpret_cast<const uint4*>(hb + (((size_t)s0) << 6) + (sub << 3));
            fma8(ev, hv, a0, a1);
        }
        if (e1 < end) {
            int s1 = sSrc[e1];
            uint4 ev = *reinterpret_cast<const uint4*>(ea_s + (((size_t)e1) << 6) + (sub << 3));
            uint4 hv = *reinterpret_cast<const uint4*>(hb + (((size_t)s1) << 6) + (sub << 3));
            fma8(ev, hv, a0, a1);
        }
    }
    // reduce across edge slots g (lane bits 3,4,5); all lanes end with bin sums
    #pragma unroll
    for (int o = 8; o < 64; o <<= 1) {
        a0.x += __shfl_xor(a0.x, o, 64);
        a0.y += __shfl_xor(a0.y, o, 64);
        a0.z += __shfl_xor(a0.z, o, 64);
        a0.w += __shfl_xor(a0.w, o, 64);
        a1.x += __shfl_xor(a1.x, o, 64);
        a1.y += __shfl_xor(a1.y, o, 64);
        a1.z += __shfl_xor(a1.z, o, 64);
        a1.w += __shfl_xor(a1.w, o, 64);
    }

    // epilogue: bias + relu + LN; sub-lane (feature-oct) reductions over 8 lanes
    const float4* bias4 = reinterpret_cast<const float4*>(bias + layer * GH + (sub << 3));
    float4 b0 = bias4[0], b1 = bias4[1];
    float4 v0, v1;
    v0.x = fmaxf(a0.x + b0.x, 0.f); v0.y = fmaxf(a0.y + b0.y, 0.f);
    v0.z = fmaxf(a0.z + b0.z, 0.f); v0.w = fmaxf(a0.w + b0.w, 0.f);
    v1.x = fmaxf(a1.x + b1.x, 0.f); v1.y = fmaxf(a1.y + b1.y, 0.f);
    v1.z = fmaxf(a1.z + b1.z, 0.f); v1.w = fmaxf(a1.w + b1.w, 0.f);
    float s = v0.x + v0.y + v0.z + v0.w + v1.x + v1.y + v1.z + v1.w;
    #pragma unroll
    for (int o = 1; o < 8; o <<= 1) s += __shfl_xor(s, o, 64);
    float mu = s * (1.0f / GH);
    float4 d0, d1;
    d0.x = v0.x - mu; d0.y = v0.y - mu; d0.z = v0.z - mu; d0.w = v0.w - mu;
    d1.x = v1.x - mu; d1.y = v1.y - mu; d1.z = v1.z - mu; d1.w = v1.w - mu;
    float q = d0.x*d0.x + d0.y*d0.y + d0.z*d0.z + d0.w*d0.w
            + d1.x*d1.x + d1.y*d1.y + d1.z*d1.z + d1.w*d1.w;
    #pragma unroll
    for (int o = 1; o < 8; o <<= 1) q += __shfl_xor(q, o, 64);
    float r = rsqrtf(q * (1.0f / GH) + LN_EPS);
    const float4* gam4 = reinterpret_cast<const float4*>(gam + layer * GH + (sub << 3));
    const float4* bet4 = reinterpret_cast<const float4*>(bet + layer * GH + (sub << 3));
    float4 g0 = gam4[0], g1 = gam4[1];
    float4 t0 = bet4[0], t1 = bet4[1];
    float4 y0, y1;
    y0.x = d0.x * r * g0.x + t0.x; y0.y = d0.y * r * g0.y + t0.y;
    y0.z = d0.z * r * g0.z + t0.z; y0.w = d0.w * r * g0.w + t0.w;
    y1.x = d1.x * r * g1.x + t1.x; y1.y = d1.y * r * g1.y + t1.y;
    y1.z = d1.z * r * g1.z + t1.z; y1.w = d1.w * r * g1.w + t1.w;

    if (g == 0) {   // lanes 0..7 own the stores (8 lanes x 2 float4 = 64 feats)
        float4* xp = reinterpret_cast<float4*>(x + (size_t)w * GH + (sub << 3));
        if (layer > 0) {
            float4 x0 = xp[0], x1 = xp[1];
            y0.x += x0.x; y0.y += x0.y; y0.z += x0.z; y0.w += x0.w;
            y1.x += x1.x; y1.y += x1.y; y1.z += x1.z; y1.w += x1.w;
        }
        if (layer < 2) {
            xp[0] = y0; xp[1] = y1;
        } else {
            float p = pres[w];
            const float4* ge4 = reinterpret_cast<const float4*>(ge + (size_t)(w & (GN - 1)) * GH + (sub << 3));
            float4 e0 = ge4[0], e1 = ge4[1];
            float4 o0, o1;
            o0.x = y0.x * p + e0.x * (1.f - p); o0.y = y0.y * p + e0.y * (1.f - p);
            o0.z = y0.z * p + e0.z * (1.f - p); o0.w = y0.w * p + e0.w * (1.f - p);
            o1.x = y1.x * p + e1.x * (1.f - p); o1.y = y1.y * p + e1.y * (1.f - p);
            o1.z = y1.z * p + e1.z * (1.f - p); o1.w = y1.w * p + e1.w * (1.f - p);
            float4* op = reinterpret_cast<float4*>(out + (size_t)w * GH + (sub << 3));
            op[0] = o0; op[1] = o1;
        }
    }
}

extern "C" void kernel_launch(void* const* d_in, const int* in_sizes, int n_in,
                              void* d_out, int out_size, void* d_ws, size_t ws_size,
                              hipStream_t stream) {
    const float* nf = (const float*)d_in[0];   // node_features f32 [8,4096,64]
    const int* ei   = (const int*)d_in[1];     // edge_indices int32 [8,2,131072]
    const float* ea = (const float*)d_in[2];   // edge_attrs f32 [8,131072,64]
    const float* W  = (const float*)d_in[3];   // [3,64,64]
    const float* bb = (const float*)d_in[4];   // [3,64]
    const float* gg = (const float*)d_in[5];   // gamma [3,64]
    const float* be = (const float*)d_in[6];   // beta  [3,64]
    const float* ge = (const float*)d_in[7];   // global_emb [4096,64]
    float* out = (float*)d_out;

    float* x    = (float*)d_ws;                       // [B*N,H] f32   (8 MB)
    float* pres = x + (size_t)NBIN * GH;              // [B*N]
    int* off    = (int*)(pres + NBIN);                // [NBIN+1]
    int* cur    = off + NBIN + 1;                     // [NBIN]
    int* hist   = cur + NBIN;                         // [NBIN]
    int* sSrc   = hist + NBIN;                        // [TOTE]        (4 MB)
    unsigned short* h_s  = (unsigned short*)(sSrc + TOTE);        // [B*N,H] bf16 (4 MB)
    unsigned short* ea_s = h_s + (size_t)NBIN * GH;               // [TOTE,H] bf16 (128 MB)

    hipMemsetAsync(hist, 0, NBIN * sizeof(int), stream);
    k_init<<<NBIN / 4, 256, 0, stream>>>(nf, pres);
    k_hist<<<TOTE / 256, 256, 0, stream>>>(ei, hist);
    k_scan<<<GB, 256, 0, stream>>>(hist, off, cur);
    k_fillperm<<<TOTE / 16, 256, 0, stream>>>(ei, cur, ea, sSrc, ea_s);

    for (int l = 0; l < 3; ++l) {
        k_gemm<<<NBIN / 4, 256, 0, stream>>>(l == 0 ? nf : x, W, h_s, l);
        k_gather<<<NBIN / 4, 256, 0, stream>>>(off, sSrc, ea_s, h_s, bb, gg, be,
                                               x, pres, ge, out, l);
    }
}